// Round 1
// baseline (94.889 us; speedup 1.0000x reference)
//
#include <hip/hip_runtime.h>

// One workgroup per image (B=4096). 196 2x2-blocks per image, each thread
// t<196 simulates the 4-qubit real circuit in 16 registers; FC layers done
// in LDS by the first wave.

__global__ __launch_bounds__(256) void hybrid_qnn_kernel(
    const float* __restrict__ x,
    const float* __restrict__ qw,
    const float* __restrict__ W1,
    const float* __restrict__ b1,
    const float* __restrict__ W2,
    const float* __restrict__ b2,
    float* __restrict__ out)
{
    __shared__ float lx[784];   // staged image
    __shared__ float lz[196];   // per-block expvals
    __shared__ float lh[32];    // FC1 activations
    __shared__ float cw[8];     // cos(qw/2)
    __shared__ float sw[8];     // sin(qw/2)

    const int img = blockIdx.x;
    const int t   = threadIdx.x;

    // coalesced stage of the image
    const float* xi = x + (size_t)img * 784;
    #pragma unroll
    for (int k = 0; k < 4; ++k) {
        int idx = t + k * 256;
        if (idx < 784) lx[idx] = xi[idx];
    }
    if (t < 8) {
        float c, s;
        sincosf(0.5f * qw[t], &s, &c);
        cw[t] = c; sw[t] = s;
    }
    __syncthreads();

    if (t < 196) {
        const int i = t / 14;
        const int j = t - 14 * i;
        const int base = i * 56 + j * 2;  // (2i)*28 + 2j
        // wire order: (a,b) = (0,0),(0,1),(1,0),(1,1)
        float c0,s0,c1,s1,c2,s2,c3,s3;
        sincosf(0.5f * lx[base],      &s0, &c0);
        sincosf(0.5f * lx[base + 1],  &s1, &c1);
        sincosf(0.5f * lx[base + 28], &s2, &c2);
        sincosf(0.5f * lx[base + 29], &s3, &c3);

        // AngleEmbedding on |0000>: product state.
        // idx = b0*8 + b1*4 + b2*2 + b3  (wire q -> bit value 8>>q)
        float st[16];
        {
            float f01[4] = {c0*c1, c0*s1, s0*c1, s0*s1};
            float f23[4] = {c2*c3, c2*s3, s2*c3, s2*s3};
            #pragma unroll
            for (int a = 0; a < 4; ++a)
                #pragma unroll
                for (int b = 0; b < 4; ++b)
                    st[a*4+b] = f01[a] * f23[b];
        }

        // MASK must be a literal so all st[] indices are compile-time
        // constants after unroll (keeps st[] in VGPRs).
#define RY_GATE(MASK, C, S) { \
        _Pragma("unroll") \
        for (int idx = 0; idx < 16; ++idx) { \
            if (!(idx & (MASK))) { \
                float u0 = st[idx], u1 = st[idx | (MASK)]; \
                st[idx]          = (C)*u0 - (S)*u1; \
                st[idx | (MASK)] = (S)*u0 + (C)*u1; \
            } \
        } }

#define CNOT_GATE(CM, TM) { \
        _Pragma("unroll") \
        for (int idx = 0; idx < 16; ++idx) { \
            if ((idx & (CM)) && !(idx & (TM))) { \
                float tmp = st[idx]; st[idx] = st[idx | (TM)]; st[idx | (TM)] = tmp; \
            } \
        } }

        // BasicEntanglerLayers: 2 layers of [RY on each wire, CNOT ring]
        #pragma unroll
        for (int l = 0; l < 2; ++l) {
            RY_GATE(8, cw[l*4+0], sw[l*4+0]);   // wire 0
            RY_GATE(4, cw[l*4+1], sw[l*4+1]);   // wire 1
            RY_GATE(2, cw[l*4+2], sw[l*4+2]);   // wire 2
            RY_GATE(1, cw[l*4+3], sw[l*4+3]);   // wire 3
            CNOT_GATE(8, 4);                    // (0,1)
            CNOT_GATE(4, 2);                    // (1,2)
            CNOT_GATE(2, 1);                    // (2,3)
            CNOT_GATE(1, 8);                    // (3,0)
        }

        // <Z0> = sum(p | b0=0) - sum(p | b0=1);  b0 is bit value 8
        float zp = 0.f, zn = 0.f;
        #pragma unroll
        for (int idx = 0; idx < 8; ++idx)  zp = fmaf(st[idx], st[idx], zp);
        #pragma unroll
        for (int idx = 8; idx < 16; ++idx) zn = fmaf(st[idx], st[idx], zn);
        lz[t] = zp - zn;
#undef RY_GATE
#undef CNOT_GATE
    }
    __syncthreads();

    // FC1: h = relu(z @ W1 + b1), W1 is (196,30) row-major.
    // lz[j] is a wave-broadcast read; W1 is 23.5 KB -> L1-resident.
    if (t < 30) {
        float acc = b1[t];
        #pragma unroll 4
        for (int j = 0; j < 196; ++j)
            acc = fmaf(lz[j], W1[j * 30 + t], acc);
        lh[t] = fmaxf(acc, 0.f);
    }
    __syncthreads();

    // FC2: out = h @ W2 + b2, W2 is (30,2) row-major.
    if (t < 2) {
        float acc = b2[t];
        #pragma unroll
        for (int k = 0; k < 30; ++k)
            acc = fmaf(lh[k], W2[k * 2 + t], acc);
        out[img * 2 + t] = acc;
    }
}

extern "C" void kernel_launch(void* const* d_in, const int* in_sizes, int n_in,
                              void* d_out, int out_size, void* d_ws, size_t ws_size,
                              hipStream_t stream) {
    const float* x  = (const float*)d_in[0];
    const float* qw = (const float*)d_in[1];
    const float* W1 = (const float*)d_in[2];
    const float* b1 = (const float*)d_in[3];
    const float* W2 = (const float*)d_in[4];
    const float* b2 = (const float*)d_in[5];
    float* out = (float*)d_out;

    const int B = in_sizes[0] / 784;   // 4096
    hipLaunchKernelGGL(hybrid_qnn_kernel, dim3(B), dim3(256), 0, stream,
                       x, qw, W1, b1, W2, b2, out);
}

// Round 2
// 85.713 us; speedup vs baseline: 1.1071x; 1.1071x over previous
//
#include <hip/hip_runtime.h>

// One workgroup (256 threads) per image (B=4096).
// t<196: simulate the 4-qubit real circuit for one 2x2 block entirely in
//        VGPRs (16-float statevector, compile-time indices) -> lz[t].
// t<240: FC1 (196->30) split 8-way per output, wave-shuffle reduce.
// t<2  : FC2 (30->2) -> out.
// Fast hardware sincos (v_sin/v_cos): args <= ~2 rad, error ~1e-6 vs 5.2e-3 tol.

__global__ __launch_bounds__(256) void hybrid_qnn_kernel(
    const float* __restrict__ x,
    const float* __restrict__ qw,
    const float* __restrict__ W1,
    const float* __restrict__ b1,
    const float* __restrict__ W2,
    const float* __restrict__ b2,
    float* __restrict__ out)
{
    __shared__ float lz[196];   // per-block expvals
    __shared__ float lh[30];    // FC1 activations

    const int img = blockIdx.x;
    const int t   = threadIdx.x;

    if (t < 196) {
        const int i = t / 14;
        const int j = t - 14 * i;
        const float* xp = x + (size_t)img * 784 + i * 56 + j * 2;
        const float2 r0 = *(const float2*)xp;          // wires 0,1
        const float2 r1 = *(const float2*)(xp + 28);   // wires 2,3

        float c0,s0,c1,s1,c2,s2,c3,s3;
        __sincosf(0.5f * r0.x, &s0, &c0);
        __sincosf(0.5f * r0.y, &s1, &c1);
        __sincosf(0.5f * r1.x, &s2, &c2);
        __sincosf(0.5f * r1.y, &s3, &c3);

        // qweights are uniform across the grid -> scalar loads; computing the
        // 8 sincos per-thread (~24 v-ops) beats an LDS round-trip + barrier.
        float cw[8], sw[8];
        #pragma unroll
        for (int k = 0; k < 8; ++k)
            __sincosf(0.5f * qw[k], &sw[k], &cw[k]);

        // AngleEmbedding on |0000>: product state.
        // idx = b0*8 + b1*4 + b2*2 + b3  (wire q -> bit mask 8>>q)
        float st[16];
        {
            float f01[4] = {c0*c1, c0*s1, s0*c1, s0*s1};
            float f23[4] = {c2*c3, c2*s3, s2*c3, s2*s3};
            #pragma unroll
            for (int a = 0; a < 4; ++a)
                #pragma unroll
                for (int b = 0; b < 4; ++b)
                    st[a*4+b] = f01[a] * f23[b];
        }

#define RY_GATE(MASK, C, S) { \
        _Pragma("unroll") \
        for (int idx = 0; idx < 16; ++idx) { \
            if (!(idx & (MASK))) { \
                float u0 = st[idx], u1 = st[idx | (MASK)]; \
                st[idx]          = (C)*u0 - (S)*u1; \
                st[idx | (MASK)] = (S)*u0 + (C)*u1; \
            } \
        } }

#define CNOT_GATE(CM, TM) { \
        _Pragma("unroll") \
        for (int idx = 0; idx < 16; ++idx) { \
            if ((idx & (CM)) && !(idx & (TM))) { \
                float tmp = st[idx]; st[idx] = st[idx | (TM)]; st[idx | (TM)] = tmp; \
            } \
        } }

        #pragma unroll
        for (int l = 0; l < 2; ++l) {
            RY_GATE(8, cw[l*4+0], sw[l*4+0]);   // wire 0
            RY_GATE(4, cw[l*4+1], sw[l*4+1]);   // wire 1
            RY_GATE(2, cw[l*4+2], sw[l*4+2]);   // wire 2
            RY_GATE(1, cw[l*4+3], sw[l*4+3]);   // wire 3
            CNOT_GATE(8, 4);                    // (0,1)
            CNOT_GATE(4, 2);                    // (1,2)
            CNOT_GATE(2, 1);                    // (2,3)
            CNOT_GATE(1, 8);                    // (3,0)
        }
#undef RY_GATE
#undef CNOT_GATE

        // <Z0> = P(b0=0) - P(b0=1); b0 = bit 8
        float zp = 0.f, zn = 0.f;
        #pragma unroll
        for (int idx = 0; idx < 8; ++idx)  zp = fmaf(st[idx], st[idx], zp);
        #pragma unroll
        for (int idx = 8; idx < 16; ++idx) zn = fmaf(st[idx], st[idx], zn);
        lz[t] = zp - zn;
    }
    __syncthreads();

    // FC1: h[o] = relu(sum_j z[j] * W1[j,o] + b1[o]); 8 segments per output,
    // shuffle-reduced within each lane-octet (no extra barrier).
    if (t < 240) {
        const int o   = t >> 3;   // 0..29
        const int seg = t & 7;    // 0..7
        float acc = 0.f;
        #pragma unroll
        for (int i = 0; i < 25; ++i) {
            const int j = seg * 25 + i;
            if (j < 196) acc = fmaf(lz[j], W1[j * 30 + o], acc);
        }
        acc += __shfl_down(acc, 4, 8);
        acc += __shfl_down(acc, 2, 8);
        acc += __shfl_down(acc, 1, 8);
        if (seg == 0) lh[o] = fmaxf(acc + b1[o], 0.f);
    }
    __syncthreads();

    // FC2: out = h @ W2 + b2, W2 is (30,2) row-major.
    if (t < 2) {
        float acc = b2[t];
        #pragma unroll
        for (int k = 0; k < 30; ++k)
            acc = fmaf(lh[k], W2[k * 2 + t], acc);
        out[img * 2 + t] = acc;
    }
}

extern "C" void kernel_launch(void* const* d_in, const int* in_sizes, int n_in,
                              void* d_out, int out_size, void* d_ws, size_t ws_size,
                              hipStream_t stream) {
    const float* x  = (const float*)d_in[0];
    const float* qw = (const float*)d_in[1];
    const float* W1 = (const float*)d_in[2];
    const float* b1 = (const float*)d_in[3];
    const float* W2 = (const float*)d_in[4];
    const float* b2 = (const float*)d_in[5];
    float* out = (float*)d_out;

    const int B = in_sizes[0] / 784;   // 4096
    hipLaunchKernelGGL(hybrid_qnn_kernel, dim3(B), dim3(256), 0, stream,
                       x, qw, W1, b1, W2, b2, out);
}

// Round 3
// 84.764 us; speedup vs baseline: 1.1194x; 1.0112x over previous
//
#include <hip/hip_runtime.h>

// One workgroup (256 threads) per image (B=4096).
// t<196: simulate the 4-qubit real circuit for one 2x2 block entirely in
//        VGPRs (16-float statevector, compile-time indices) -> lz[t].
// Key algebraic fusion: AngleEmbedding RY(x_i) is immediately followed by
// layer-0 entangler RY(w0_i) on the same wire -> RY(x_i + w0_i). The product
// state is built directly from the summed angles, deleting 4 gate
// applications (128 FMAs) and 4 sincos per lane.
// t<240: FC1 (196->30) split 8-way per output, wave-shuffle reduce.
// t<2  : FC2 (30->2) -> out.

__global__ __launch_bounds__(256) void hybrid_qnn_kernel(
    const float* __restrict__ x,
    const float* __restrict__ qw,
    const float* __restrict__ W1,
    const float* __restrict__ b1,
    const float* __restrict__ W2,
    const float* __restrict__ b2,
    float* __restrict__ out)
{
    __shared__ float lz[196];   // per-block expvals
    __shared__ float lh[30];    // FC1 activations

    const int img = blockIdx.x;
    const int t   = threadIdx.x;

    if (t < 196) {
        const int i = t / 14;
        const int j = t - 14 * i;
        const float* xp = x + (size_t)img * 784 + i * 56 + j * 2;
        const float2 r0 = *(const float2*)xp;          // wires 0,1
        const float2 r1 = *(const float2*)(xp + 28);   // wires 2,3

        // Fused embedding + layer-0 RY angles (qw[0..3] uniform -> s_loads).
        float c0,s0,c1,s1,c2,s2,c3,s3;
        __sincosf(0.5f * (r0.x + qw[0]), &s0, &c0);
        __sincosf(0.5f * (r0.y + qw[1]), &s1, &c1);
        __sincosf(0.5f * (r1.x + qw[2]), &s2, &c2);
        __sincosf(0.5f * (r1.y + qw[3]), &s3, &c3);

        // Layer-1 RY angles (uniform).
        float cw[4], sw[4];
        #pragma unroll
        for (int k = 0; k < 4; ++k)
            __sincosf(0.5f * qw[4 + k], &sw[k], &cw[k]);

        // Product state after fused RYs.
        // idx = b0*8 + b1*4 + b2*2 + b3  (wire q -> bit mask 8>>q)
        float st[16];
        {
            float f01[4] = {c0*c1, c0*s1, s0*c1, s0*s1};
            float f23[4] = {c2*c3, c2*s3, s2*c3, s2*s3};
            #pragma unroll
            for (int a = 0; a < 4; ++a)
                #pragma unroll
                for (int b = 0; b < 4; ++b)
                    st[a*4+b] = f01[a] * f23[b];
        }

#define RY_GATE(MASK, C, S) { \
        _Pragma("unroll") \
        for (int idx = 0; idx < 16; ++idx) { \
            if (!(idx & (MASK))) { \
                float u0 = st[idx], u1 = st[idx | (MASK)]; \
                st[idx]          = (C)*u0 - (S)*u1; \
                st[idx | (MASK)] = (S)*u0 + (C)*u1; \
            } \
        } }

#define CNOT_GATE(CM, TM) { \
        _Pragma("unroll") \
        for (int idx = 0; idx < 16; ++idx) { \
            if ((idx & (CM)) && !(idx & (TM))) { \
                float tmp = st[idx]; st[idx] = st[idx | (TM)]; st[idx | (TM)] = tmp; \
            } \
        } }

        // Layer 0 CNOT ring (RYs already fused into the product state).
        CNOT_GATE(8, 4);                    // (0,1)
        CNOT_GATE(4, 2);                    // (1,2)
        CNOT_GATE(2, 1);                    // (2,3)
        CNOT_GATE(1, 8);                    // (3,0)
        // Layer 1: RYs + CNOT ring.
        RY_GATE(8, cw[0], sw[0]);           // wire 0
        RY_GATE(4, cw[1], sw[1]);           // wire 1
        RY_GATE(2, cw[2], sw[2]);           // wire 2
        RY_GATE(1, cw[3], sw[3]);           // wire 3
        CNOT_GATE(8, 4);
        CNOT_GATE(4, 2);
        CNOT_GATE(2, 1);
        CNOT_GATE(1, 8);
#undef RY_GATE
#undef CNOT_GATE

        // <Z0> = P(b0=0) - P(b0=1); b0 = bit 8
        float zp = 0.f, zn = 0.f;
        #pragma unroll
        for (int idx = 0; idx < 8; ++idx)  zp = fmaf(st[idx], st[idx], zp);
        #pragma unroll
        for (int idx = 8; idx < 16; ++idx) zn = fmaf(st[idx], st[idx], zn);
        lz[t] = zp - zn;
    }
    __syncthreads();

    // FC1: h[o] = relu(sum_j z[j] * W1[j,o] + b1[o]); 8 segments per output,
    // shuffle-reduced within each lane-octet (no extra barrier).
    if (t < 240) {
        const int o   = t >> 3;   // 0..29
        const int seg = t & 7;    // 0..7
        float acc = 0.f;
        #pragma unroll
        for (int i = 0; i < 25; ++i) {
            const int j = seg * 25 + i;
            if (j < 196) acc = fmaf(lz[j], W1[j * 30 + o], acc);
        }
        acc += __shfl_down(acc, 4, 8);
        acc += __shfl_down(acc, 2, 8);
        acc += __shfl_down(acc, 1, 8);
        if (seg == 0) lh[o] = fmaxf(acc + b1[o], 0.f);
    }
    __syncthreads();

    // FC2: out = h @ W2 + b2, W2 is (30,2) row-major.
    if (t < 2) {
        float acc = b2[t];
        #pragma unroll
        for (int k = 0; k < 30; ++k)
            acc = fmaf(lh[k], W2[k * 2 + t], acc);
        out[img * 2 + t] = acc;
    }
}

extern "C" void kernel_launch(void* const* d_in, const int* in_sizes, int n_in,
                              void* d_out, int out_size, void* d_ws, size_t ws_size,
                              hipStream_t stream) {
    const float* x  = (const float*)d_in[0];
    const float* qw = (const float*)d_in[1];
    const float* W1 = (const float*)d_in[2];
    const float* b1 = (const float*)d_in[3];
    const float* W2 = (const float*)d_in[4];
    const float* b2 = (const float*)d_in[5];
    float* out = (float*)d_out;

    const int B = in_sizes[0] / 784;   // 4096
    hipLaunchKernelGGL(hybrid_qnn_kernel, dim3(B), dim3(256), 0, stream,
                       x, qw, W1, b1, W2, b2, out);
}